// Round 6
// baseline (479.296 us; speedup 1.0000x reference)
//
#include <hip/hip_runtime.h>

#define N_USER   100000
#define N_ITEM   150000
#define N_NODES  250000
#define N_HID    64
#define E_UI     1000000
#define E_S      1000000
#define N_TOT    (N_NODES + N_USER)      // 350000
#define E_TOT    (E_UI + E_S)            // 2000000

#define BR     64                         // rows per block (spmm)
#define SMSTR  68                         // padded agg-stage row stride (floats)
#define CH     4096                       // edges per bin_pass1 chunk
#define RPB    2048                       // rows per coarse bucket
#define RPB_SH 11
#define NBKT   ((N_TOT + RPB - 1) / RPB)  // 171
#define FS     8                          // sub-blocks per bucket in fine_pass2

typedef unsigned long long ull;

// ===========================================================================
// histogram + scan (CSR rowStart over combined 350K rows)
// ===========================================================================
__global__ __launch_bounds__(256) void edge_hist2(const int* __restrict__ ui_rows,
                                                  const int* __restrict__ s_rows,
                                                  int* __restrict__ counts) {
    int i = blockIdx.x * 256 + threadIdx.x;
    if (i < E_UI)            atomicAdd(&counts[ui_rows[i]], 1);
    else if (i < E_TOT)      atomicAdd(&counts[N_NODES + s_rows[i - E_UI]], 1);
}

__global__ __launch_bounds__(256) void scan_block512(int* __restrict__ data,
                                                     int* __restrict__ blockSums, int n) {
    __shared__ int sm[512];
    int t = threadIdx.x;
    int base = blockIdx.x * 512;
    int i0 = base + t, i1 = base + t + 256;
    int v0 = (i0 < n) ? data[i0] : 0;
    int v1 = (i1 < n) ? data[i1] : 0;
    sm[t] = v0; sm[t + 256] = v1;
    __syncthreads();
    for (int off = 1; off < 512; off <<= 1) {
        int a = (t >= off) ? sm[t - off] : 0;
        int b = (t + 256 >= off) ? sm[t + 256 - off] : 0;
        __syncthreads();
        sm[t] += a; sm[t + 256] += b;
        __syncthreads();
    }
    if (i0 < n) data[i0] = sm[t] - v0;
    if (i1 < n) data[i1] = sm[t + 256] - v1;
    if (t == 255) blockSums[blockIdx.x] = sm[511];
}

__global__ __launch_bounds__(1024) void scan_sums(int* __restrict__ blockSums, int nb) {
    __shared__ int sm[1024];
    int v = (threadIdx.x < nb) ? blockSums[threadIdx.x] : 0;
    sm[threadIdx.x] = v;
    __syncthreads();
    for (int off = 1; off < 1024; off <<= 1) {
        int t = (threadIdx.x >= off) ? sm[threadIdx.x - off] : 0;
        __syncthreads();
        sm[threadIdx.x] += t;
        __syncthreads();
    }
    if (threadIdx.x < nb) blockSums[threadIdx.x] = sm[threadIdx.x] - v;
}

// finalize rowStart; seed per-row global cursors and per-bucket coarse cursors
__global__ __launch_bounds__(256) void scan_add512(int* __restrict__ data,
                                                   const int* __restrict__ blockSums,
                                                   int* __restrict__ rowCur,
                                                   int* __restrict__ bucketCur,
                                                   int n, int total) {
    int base = blockIdx.x * 512;
    int s = blockSums[blockIdx.x];
#pragma unroll
    for (int k = 0; k < 2; ++k) {
        int i = base + threadIdx.x + k * 256;
        if (i < n) {
            int v = data[i] + s;
            data[i] = v;
            rowCur[i] = v;
            if ((i & (RPB - 1)) == 0) bucketCur[i >> RPB_SH] = v;
        }
    }
    if (blockIdx.x == 0 && threadIdx.x == 0) data[n] = total;
}

// ===========================================================================
// pass 1: LDS binning by coarse bucket; coalesced bucket-run writes to pairsA
//   entry = v<<32 | rLow<<19 | c   (rLow<2048 @bits19..29; c<2^19)
// ===========================================================================
__global__ __launch_bounds__(256) void bin_pass1(const int* __restrict__ ui_rows,
                                                 const int* __restrict__ ui_cols,
                                                 const float* __restrict__ ui_vals,
                                                 const int* __restrict__ s_rows,
                                                 const int* __restrict__ s_cols,
                                                 const float* __restrict__ s_vals,
                                                 int* __restrict__ bucketCur,
                                                 ull* __restrict__ pairsA) {
    __shared__ ull            staged[CH];
    __shared__ unsigned short bkt[CH];
    __shared__ unsigned short ord[CH];
    __shared__ int hist[256];
    __shared__ int lstart[256];
    __shared__ int cnt2[256];
    __shared__ int baseg[256];
    const int t = threadIdx.x;
    hist[t] = 0; cnt2[t] = 0;
    __syncthreads();

    const int e0 = blockIdx.x * CH;
    const int n  = min(CH, E_TOT - e0);

    for (int i = t; i < n; i += 256) {
        int g = e0 + i, r, c; float v;
        if (g < E_UI) { r = ui_rows[g];            c = ui_cols[g];            v = ui_vals[g]; }
        else          { int k = g - E_UI;
                        r = N_NODES + s_rows[k];   c = N_NODES + s_cols[k];   v = s_vals[k]; }
        int b = r >> RPB_SH;
        staged[i] = ((ull)__float_as_uint(v) << 32) |
                    ((ull)(unsigned)(r & (RPB - 1)) << 19) | (unsigned)c;
        bkt[i] = (unsigned short)b;
        atomicAdd(&hist[b], 1);
    }
    __syncthreads();

    int hv = hist[t];
    lstart[t] = hv;
    __syncthreads();
    for (int off = 1; off < 256; off <<= 1) {
        int a = (t >= off) ? lstart[t - off] : 0;
        __syncthreads();
        lstart[t] += a;
        __syncthreads();
    }
    int incl = lstart[t];
    __syncthreads();
    lstart[t] = incl - hv;
    if (t < NBKT && hv > 0) baseg[t] = atomicAdd(&bucketCur[t], hv);
    __syncthreads();

    for (int i = t; i < n; i += 256) {
        int b = bkt[i];
        int l = atomicAdd(&cnt2[b], 1);
        ord[lstart[b] + l] = (unsigned short)i;
    }
    __syncthreads();

    for (int k = t; k < n; k += 256) {
        int i = ord[k];
        int b = bkt[i];
        pairsA[(size_t)baseg[b] + (k - lstart[b])] = staged[i];
    }
}

// ===========================================================================
// pass 2: per-bucket fine scatter, FS blocks per bucket, global row cursors;
// writes confined to the bucket's ~94KB window -> L2-local
// ===========================================================================
__global__ __launch_bounds__(256) void fine_pass2(const ull* __restrict__ pairsA,
                                                  const int* __restrict__ rowStart,
                                                  int* __restrict__ rowCur,
                                                  ull* __restrict__ pairs) {
    const int b   = blockIdx.x >> 3;          // FS = 8
    const int sub = blockIdx.x & (FS - 1);
    const int r0  = b * RPB;
    const int rEnd = min(r0 + RPB, N_TOT);
    const int s0 = rowStart[r0];
    const int e0 = rowStart[rEnd];
    for (int j = s0 + sub * 256 + threadIdx.x; j < e0; j += FS * 256) {
        ull e = pairsA[j];
        int r = r0 + (int)((e >> 19) & (RPB - 1));
        int pos = atomicAdd(&rowCur[r], 1);
        pairs[pos] = (e & 0xFFFFFFFF00000000ull) | (e & 0x7FFFFull);
    }
}

// ===========================================================================
// spmm_w: quarter-wave per destination row; aggregate RAW rows, then apply
// W in epilogue (linearity: spmm(X@W) == spmm(X)@W), leaky, l2norm.
//   LAYER 1: gather from input embeddings; out = emb[row] + n1; B2out = lv1
//   LAYER 2: gather from B2; out += n2
// ===========================================================================
template <int LAYER>
__global__ __launch_bounds__(256) void spmm_w(const ull* __restrict__ pairs,
                                              const int* __restrict__ rowStart,
                                              const float* __restrict__ u,
                                              const float* __restrict__ it,
                                              const float* __restrict__ B2in,
                                              float* __restrict__ B2out,
                                              const float* __restrict__ Wui,
                                              const float* __restrict__ Wsoc,
                                              float* __restrict__ out_ui,
                                              float* __restrict__ out_s,
                                              int uiBlocks) {
    __shared__ float Wsm[N_HID * N_HID];
    __shared__ float smX[4][4 * SMSTR];
    const int tid = threadIdx.x;
    const bool isUI = (int)blockIdx.x < uiBlocks;
    const int bl    = isUI ? blockIdx.x : blockIdx.x - uiBlocks;
    const int rbeg  = isUI ? bl * BR : N_NODES + bl * BR;
    const int rlim  = isUI ? min(BR, N_NODES - bl * BR) : min(BR, N_USER - bl * BR);

    const float* W = isUI ? Wui : Wsoc;
#pragma unroll
    for (int c = 0; c < 4; ++c)
        *(float4*)&Wsm[c * 1024 + tid * 4] = *(const float4*)&W[c * 1024 + tid * 4];
    __syncthreads();

    const int w  = tid >> 6;
    const int q  = (tid >> 4) & 3;
    const int l4 = (tid & 15) * 4;
    float* smx = &smX[w][q * SMSTR];

    for (int i = 0; i < 4; ++i) {
        int row = rbeg + w * 16 + i * 4 + q;
        if (row >= rbeg + rlim) continue;
        int s = rowStart[row];
        int e = rowStart[row + 1];
        float4 acc = make_float4(0.f, 0.f, 0.f, 0.f);
        for (int j = s; j < e; j += 8) {
            int last = e - 1;
            ull p[8]; float4 g[8]; float vv[8];
#pragma unroll
            for (int k = 0; k < 8; ++k) p[k] = pairs[min(j + k, last)];
#pragma unroll
            for (int k = 0; k < 8; ++k) {
                unsigned c = (unsigned)p[k];           // low 19 bits (pre-masked)
                const float* src;
                if (LAYER == 1) {
                    src = (c < N_USER)   ? u  + (size_t)c * N_HID
                        : (c < N_NODES)  ? it + (size_t)(c - N_USER) * N_HID
                                         : u  + (size_t)(c - N_NODES) * N_HID;
                } else {
                    src = B2in + (size_t)c * N_HID;
                }
                g[k] = *(const float4*)(src + l4);
            }
#pragma unroll
            for (int k = 0; k < 8; ++k)
                vv[k] = (j + k < e) ? __uint_as_float((unsigned)(p[k] >> 32)) : 0.f;
#pragma unroll
            for (int k = 0; k < 8; ++k) {
                acc.x = fmaf(vv[k], g[k].x, acc.x);
                acc.y = fmaf(vv[k], g[k].y, acc.y);
                acc.z = fmaf(vv[k], g[k].z, acc.z);
                acc.w = fmaf(vv[k], g[k].w, acc.w);
            }
        }

        // stage aggregated row, apply W (z = agg @ W)
        *(float4*)&smx[l4] = acc;
        asm volatile("s_waitcnt lgkmcnt(0)" ::: "memory");
        float4 z = make_float4(0.f, 0.f, 0.f, 0.f);
#pragma unroll
        for (int k4 = 0; k4 < 16; ++k4) {
            float4 x4 = *(const float4*)&smx[k4 * 4];
            const float* wr = &Wsm[(k4 * 4) * N_HID + l4];
            float4 w0 = *(const float4*)(wr);
            float4 w1 = *(const float4*)(wr + N_HID);
            float4 w2 = *(const float4*)(wr + 2 * N_HID);
            float4 w3 = *(const float4*)(wr + 3 * N_HID);
            z.x = fmaf(x4.x, w0.x, z.x); z.x = fmaf(x4.y, w1.x, z.x);
            z.x = fmaf(x4.z, w2.x, z.x); z.x = fmaf(x4.w, w3.x, z.x);
            z.y = fmaf(x4.x, w0.y, z.y); z.y = fmaf(x4.y, w1.y, z.y);
            z.y = fmaf(x4.z, w2.y, z.y); z.y = fmaf(x4.w, w3.y, z.y);
            z.z = fmaf(x4.x, w0.z, z.z); z.z = fmaf(x4.y, w1.z, z.z);
            z.z = fmaf(x4.z, w2.z, z.z); z.z = fmaf(x4.w, w3.z, z.z);
            z.w = fmaf(x4.x, w0.w, z.w); z.w = fmaf(x4.y, w1.w, z.w);
            z.w = fmaf(x4.z, w2.w, z.w); z.w = fmaf(x4.w, w3.w, z.w);
        }

        float4 lv;
        lv.x = (z.x >= 0.f) ? z.x : 0.5f * z.x;
        lv.y = (z.y >= 0.f) ? z.y : 0.5f * z.y;
        lv.z = (z.z >= 0.f) ? z.z : 0.5f * z.z;
        lv.w = (z.w >= 0.f) ? z.w : 0.5f * z.w;
        float ss = lv.x * lv.x + lv.y * lv.y + lv.z * lv.z + lv.w * lv.w;
        ss += __shfl_xor(ss, 1, 64);
        ss += __shfl_xor(ss, 2, 64);
        ss += __shfl_xor(ss, 4, 64);
        ss += __shfl_xor(ss, 8, 64);
        float inv = 1.f / fmaxf(sqrtf(ss), 1e-12f);

        float* op = isUI ? out_ui + (size_t)row * N_HID
                         : out_s  + (size_t)(row - N_NODES) * N_HID;
        if (LAYER == 1) {
            const float* erow = isUI
                ? ((row < N_USER) ? u + (size_t)row * N_HID
                                  : it + (size_t)(row - N_USER) * N_HID)
                : u + (size_t)(row - N_NODES) * N_HID;
            float4 e4 = *(const float4*)&erow[l4];
            float4 o;
            o.x = fmaf(lv.x, inv, e4.x); o.y = fmaf(lv.y, inv, e4.y);
            o.z = fmaf(lv.z, inv, e4.z); o.w = fmaf(lv.w, inv, e4.w);
            *(float4*)&op[l4] = o;
            *(float4*)&B2out[(size_t)row * N_HID + l4] = lv;
        } else {
            float4 o = *(float4*)&op[l4];
            o.x = fmaf(lv.x, inv, o.x); o.y = fmaf(lv.y, inv, o.y);
            o.z = fmaf(lv.z, inv, o.z); o.w = fmaf(lv.w, inv, o.w);
            *(float4*)&op[l4] = o;
        }
    }
}

// ===========================================================================
// Atomic fallback (only if ws too small for the sorted path)
// ===========================================================================
__global__ __launch_bounds__(256) void init_concat(const float* __restrict__ u,
                                                   const float* __restrict__ it,
                                                   float* __restrict__ A,
                                                   float* __restrict__ out) {
    int i = blockIdx.x * 256 + threadIdx.x;
    const int nu4 = N_USER * N_HID / 4;
    const int nt4 = N_NODES * N_HID / 4;
    if (i >= nt4) return;
    float4 v = (i < nu4) ? ((const float4*)u)[i] : ((const float4*)it)[i - nu4];
    ((float4*)A)[i]   = v;
    ((float4*)out)[i] = v;
}

__global__ __launch_bounds__(256) void copy2(const float* __restrict__ src,
                                             float* __restrict__ d0,
                                             float* __restrict__ d1, int n4) {
    int i = blockIdx.x * 256 + threadIdx.x;
    if (i >= n4) return;
    float4 v = ((const float4*)src)[i];
    ((float4*)d0)[i] = v;
    ((float4*)d1)[i] = v;
}

__global__ __launch_bounds__(256) void gemm64(const float* __restrict__ X,
                                              const float* __restrict__ W,
                                              float* __restrict__ Y, int nrows) {
    __shared__ float Ws[N_HID * N_HID];
    int tid = threadIdx.x;
#pragma unroll
    for (int c = 0; c < 16; ++c) Ws[c * 256 + tid] = W[c * 256 + tid];
    __syncthreads();
    int row = blockIdx.x * 256 + tid;
    if (row >= nrows) return;
    float x[N_HID];
    const float4* xr = (const float4*)(X + (size_t)row * N_HID);
#pragma unroll
    for (int c = 0; c < 16; ++c) {
        float4 v = xr[c];
        x[4*c+0] = v.x; x[4*c+1] = v.y; x[4*c+2] = v.z; x[4*c+3] = v.w;
    }
    float4* y4 = (float4*)(Y + (size_t)row * N_HID);
    for (int jc = 0; jc < 16; ++jc) {
        float4 a = make_float4(0.f,0.f,0.f,0.f);
#pragma unroll
        for (int k = 0; k < N_HID; ++k) {
            float4 wv = *((const float4*)&Ws[k * N_HID + jc * 4]);
            a.x += x[k]*wv.x; a.y += x[k]*wv.y; a.z += x[k]*wv.z; a.w += x[k]*wv.w;
        }
        y4[jc] = a;
    }
}

__global__ __launch_bounds__(256) void spmm_scatter(const int* __restrict__ rows,
                                                    const int* __restrict__ cols,
                                                    const float* __restrict__ vals,
                                                    const float* __restrict__ X,
                                                    float* __restrict__ Y, int nedges) {
    long long t = (long long)blockIdx.x * 256 + threadIdx.x;
    int e = (int)(t >> 6);
    int h = (int)(t & 63);
    if (e >= nedges) return;
    atomicAdd(&Y[rows[e] * N_HID + h], vals[e] * X[cols[e] * N_HID + h]);
}

__global__ __launch_bounds__(256) void leaky_norm_acc(float* __restrict__ Y,
                                                      float* __restrict__ out, int nrows) {
    int row = blockIdx.x * 4 + (threadIdx.x >> 6);
    int h   = threadIdx.x & 63;
    if (row >= nrows) return;
    int idx = row * N_HID + h;
    float v = Y[idx];
    v = (v >= 0.f) ? v : 0.5f * v;
    Y[idx] = v;
    float s = v * v;
#pragma unroll
    for (int off = 32; off > 0; off >>= 1) s += __shfl_xor(s, off, 64);
    out[idx] += v / fmaxf(sqrtf(s), 1e-12f);
}

// ===========================================================================
extern "C" void kernel_launch(void* const* d_in, const int* in_sizes, int n_in,
                              void* d_out, int out_size, void* d_ws, size_t ws_size,
                              hipStream_t stream) {
    const float* user_emb = (const float*)d_in[0];
    const float* item_emb = (const float*)d_in[1];
    const float* ui_w     = (const float*)d_in[2];
    const float* s_w      = (const float*)d_in[3];
    const int*   ui_rows  = (const int*)d_in[4];
    const int*   ui_cols  = (const int*)d_in[5];
    const float* ui_vals  = (const float*)d_in[6];
    const int*   s_rows   = (const int*)d_in[7];
    const int*   s_cols   = (const int*)d_in[8];
    const float* s_vals   = (const float*)d_in[9];

    float* out_ui = (float*)d_out;
    float* out_s  = (float*)d_out + (size_t)N_NODES * N_HID;

    const size_t szUI  = (size_t)N_NODES * N_HID * sizeof(float);   // 64.0 MB
    const size_t szTOT = (size_t)N_TOT   * N_HID * sizeof(float);   // 89.6 MB
    const size_t rsPad = 1400832;                                   // (N_TOT+1)*4 padded

    const int uiBlocks = (N_NODES + BR - 1) / BR;    // 3907
    const int sBlocks  = (N_USER  + BR - 1) / BR;    // 1563
    const int nbScan   = (N_TOT + 511) / 512;
    const int nbE      = (E_TOT + 255) / 256;
    const int nbP1     = (E_TOT + CH - 1) / CH;      // 489

    const size_t needBytes = szTOT + (size_t)E_TOT * 8 + 2 * rsPad + 8192 + 4096; // ~108.5 MB

    if (ws_size >= needBytes) {
        float* B2 = (float*)d_ws;                     // lv1 buffer (layer-2 gather src)
        char*  p  = (char*)d_ws + szTOT;
        ull* pairs     = (ull*)p;            p += (size_t)E_TOT * 8;
        int* rowStart  = (int*)p;            p += rsPad;
        int* rowCur    = (int*)p;            p += rsPad;
        int* blockSums = (int*)p;            p += 8192;
        int* bucketCur = (int*)p;
        ull* pairsA    = (ull*)B2;           // sort staging aliases B2 (dead until spmm1)

        // ---- sort: hist -> scan -> LDS-binned coarse scatter -> L2-local fine scatter
        hipMemsetAsync(rowStart, 0, (size_t)N_TOT * 4, stream);
        edge_hist2<<<nbE, 256, 0, stream>>>(ui_rows, s_rows, rowStart);
        scan_block512<<<nbScan, 256, 0, stream>>>(rowStart, blockSums, N_TOT);
        scan_sums<<<1, 1024, 0, stream>>>(blockSums, nbScan);
        scan_add512<<<nbScan, 256, 0, stream>>>(rowStart, blockSums, rowCur, bucketCur,
                                                N_TOT, E_TOT);
        bin_pass1<<<nbP1, 256, 0, stream>>>(ui_rows, ui_cols, ui_vals,
                                            s_rows, s_cols, s_vals, bucketCur, pairsA);
        fine_pass2<<<NBKT * FS, 256, 0, stream>>>(pairsA, rowStart, rowCur, pairs);

        // ---- 2 fused spmm dispatches (W applied post-aggregation in epilogue)
        const int grid = uiBlocks + sBlocks;
        spmm_w<1><<<grid, 256, 0, stream>>>(pairs, rowStart, user_emb, item_emb,
                                            nullptr, B2, ui_w, s_w,
                                            out_ui, out_s, uiBlocks);
        spmm_w<2><<<grid, 256, 0, stream>>>(pairs, rowStart, user_emb, item_emb,
                                            B2, nullptr,
                                            ui_w + N_HID * N_HID, s_w + N_HID * N_HID,
                                            out_ui, out_s, uiBlocks);
        return;
    }

    // ------------------- fallback: atomic path -------------------
    float* A = (float*)d_ws;
    float* B = (float*)((char*)d_ws + szUI);
    init_concat<<<(N_NODES * N_HID / 4 + 255) / 256, 256, 0, stream>>>(
        user_emb, item_emb, A, out_ui);
    for (int l = 0; l < 2; ++l) {
        gemm64<<<(N_NODES + 255) / 256, 256, 0, stream>>>(
            A, ui_w + l * N_HID * N_HID, B, N_NODES);
        hipMemsetAsync(A, 0, szUI, stream);
        spmm_scatter<<<(int)(((long long)E_UI * 64) / 256), 256, 0, stream>>>(
            ui_rows, ui_cols, ui_vals, B, A, E_UI);
        leaky_norm_acc<<<(N_NODES + 3) / 4, 256, 0, stream>>>(A, out_ui, N_NODES);
    }
    copy2<<<(N_USER * N_HID / 4 + 255) / 256, 256, 0, stream>>>(
        user_emb, A, out_s, N_USER * N_HID / 4);
    const size_t sBytes = (size_t)N_USER * N_HID * sizeof(float);
    for (int l = 0; l < 2; ++l) {
        gemm64<<<(N_USER + 255) / 256, 256, 0, stream>>>(
            A, s_w + l * N_HID * N_HID, B, N_USER);
        hipMemsetAsync(A, 0, sBytes, stream);
        spmm_scatter<<<(int)(((long long)E_S * 64) / 256), 256, 0, stream>>>(
            s_rows, s_cols, s_vals, B, A, E_S);
        leaky_norm_acc<<<(N_USER + 3) / 4, 256, 0, stream>>>(A, out_s, N_USER);
    }
}

// Round 7
// 347.312 us; speedup vs baseline: 1.3800x; 1.3800x over previous
//
#include <hip/hip_runtime.h>

#define N_USER   100000
#define N_ITEM   150000
#define N_NODES  250000
#define N_HID    64
#define E_UI     1000000
#define E_S      1000000
#define N_TOT    (N_NODES + N_USER)      // 350000
#define E_TOT    (E_UI + E_S)            // 2000000

#define BR     64                         // rows per block (spmm)
#define SMSTR  68                         // padded agg-stage row stride (floats)
#define CH     4096                       // edges per bin_pass1 chunk
#define RPB    1024                       // rows per coarse bucket
#define RPB_SH 10
#define NBKT   ((N_TOT + RPB - 1) / RPB)  // 342
#define NBKTP  512                        // padded bucket-array size (scan width)

typedef unsigned long long ull;

__device__ __forceinline__ unsigned short f_to_bf(float f) {
    unsigned u = __float_as_uint(f);
    u += 0x7FFF + ((u >> 16) & 1);                 // round-to-nearest-even
    return (unsigned short)(u >> 16);
}
__device__ __forceinline__ float bf_to_f(unsigned short s) {
    return __uint_as_float((unsigned)s << 16);
}

// ===========================================================================
// histogram + scan (CSR rowStart over combined 350K rows)
// ===========================================================================
__global__ __launch_bounds__(256) void edge_hist2(const int* __restrict__ ui_rows,
                                                  const int* __restrict__ s_rows,
                                                  int* __restrict__ counts) {
    int i = blockIdx.x * 256 + threadIdx.x;
    if (i < E_UI)            atomicAdd(&counts[ui_rows[i]], 1);
    else if (i < E_TOT)      atomicAdd(&counts[N_NODES + s_rows[i - E_UI]], 1);
}

__global__ __launch_bounds__(256) void scan_block512(int* __restrict__ data,
                                                     int* __restrict__ blockSums, int n) {
    __shared__ int sm[512];
    int t = threadIdx.x;
    int base = blockIdx.x * 512;
    int i0 = base + t, i1 = base + t + 256;
    int v0 = (i0 < n) ? data[i0] : 0;
    int v1 = (i1 < n) ? data[i1] : 0;
    sm[t] = v0; sm[t + 256] = v1;
    __syncthreads();
    for (int off = 1; off < 512; off <<= 1) {
        int a = (t >= off) ? sm[t - off] : 0;
        int b = (t + 256 >= off) ? sm[t + 256 - off] : 0;
        __syncthreads();
        sm[t] += a; sm[t + 256] += b;
        __syncthreads();
    }
    if (i0 < n) data[i0] = sm[t] - v0;
    if (i1 < n) data[i1] = sm[t + 256] - v1;
    if (t == 255) blockSums[blockIdx.x] = sm[511];
}

__global__ __launch_bounds__(1024) void scan_sums(int* __restrict__ blockSums, int nb) {
    __shared__ int sm[1024];
    int v = (threadIdx.x < nb) ? blockSums[threadIdx.x] : 0;
    sm[threadIdx.x] = v;
    __syncthreads();
    for (int off = 1; off < 1024; off <<= 1) {
        int t = (threadIdx.x >= off) ? sm[threadIdx.x - off] : 0;
        __syncthreads();
        sm[threadIdx.x] += t;
        __syncthreads();
    }
    if (threadIdx.x < nb) blockSums[threadIdx.x] = sm[threadIdx.x] - v;
}

// finalize rowStart; seed per-bucket coarse write cursors
__global__ __launch_bounds__(256) void scan_add512(int* __restrict__ data,
                                                   const int* __restrict__ blockSums,
                                                   int* __restrict__ bucketCur,
                                                   int n, int total) {
    int base = blockIdx.x * 512;
    int s = blockSums[blockIdx.x];
#pragma unroll
    for (int k = 0; k < 2; ++k) {
        int i = base + threadIdx.x + k * 256;
        if (i < n) {
            int v = data[i] + s;
            data[i] = v;
            if ((i & (RPB - 1)) == 0) bucketCur[i >> RPB_SH] = v;
        }
    }
    if (blockIdx.x == 0 && threadIdx.x == 0) data[n] = total;
}

// ===========================================================================
// pass 1: LDS binning by coarse bucket (342 buckets of 1024 rows);
// coalesced bucket-run writes to pairsA.
//   entry = v<<32 | rLow<<19 | c   (rLow<1024 @bits19..28; c<2^19)
// ===========================================================================
__global__ __launch_bounds__(256) void bin_pass1(const int* __restrict__ ui_rows,
                                                 const int* __restrict__ ui_cols,
                                                 const float* __restrict__ ui_vals,
                                                 const int* __restrict__ s_rows,
                                                 const int* __restrict__ s_cols,
                                                 const float* __restrict__ s_vals,
                                                 int* __restrict__ bucketCur,
                                                 ull* __restrict__ pairsA) {
    __shared__ ull            staged[CH];
    __shared__ unsigned short bkt[CH];
    __shared__ unsigned short ord[CH];
    __shared__ int hist[NBKTP];
    __shared__ int lstart[NBKTP];
    __shared__ int cnt2[NBKTP];
    __shared__ int baseg[NBKTP];
    const int t = threadIdx.x;
    hist[t] = 0; hist[t + 256] = 0;
    cnt2[t] = 0; cnt2[t + 256] = 0;
    __syncthreads();

    const int e0 = blockIdx.x * CH;
    const int n  = min(CH, E_TOT - e0);

    for (int i = t; i < n; i += 256) {
        int g = e0 + i, r, c; float v;
        if (g < E_UI) { r = ui_rows[g];            c = ui_cols[g];            v = ui_vals[g]; }
        else          { int k = g - E_UI;
                        r = N_NODES + s_rows[k];   c = N_NODES + s_cols[k];   v = s_vals[k]; }
        int b = r >> RPB_SH;
        staged[i] = ((ull)__float_as_uint(v) << 32) |
                    ((ull)(unsigned)(r & (RPB - 1)) << 19) | (unsigned)c;
        bkt[i] = (unsigned short)b;
        atomicAdd(&hist[b], 1);
    }
    __syncthreads();

    // exclusive scan of hist[0..511] (2 elems/thread, Hillis–Steele)
    int v0 = hist[t], v1 = hist[t + 256];
    lstart[t] = v0; lstart[t + 256] = v1;
    __syncthreads();
    for (int off = 1; off < NBKTP; off <<= 1) {
        int a = (t >= off) ? lstart[t - off] : 0;
        int b = (t + 256 >= off) ? lstart[t + 256 - off] : 0;
        __syncthreads();
        lstart[t] += a; lstart[t + 256] += b;
        __syncthreads();
    }
    int ex0 = lstart[t] - v0, ex1 = lstart[t + 256] - v1;
    __syncthreads();
    lstart[t] = ex0; lstart[t + 256] = ex1;
    if (v0 > 0) baseg[t] = atomicAdd(&bucketCur[t], v0);
    if (v1 > 0) baseg[t + 256] = atomicAdd(&bucketCur[t + 256], v1);
    __syncthreads();

    for (int i = t; i < n; i += 256) {
        int b = bkt[i];
        int l = atomicAdd(&cnt2[b], 1);
        ord[lstart[b] + l] = (unsigned short)i;
    }
    __syncthreads();

    for (int k = t; k < n; k += 256) {
        int i = ord[k];
        int b = bkt[i];
        pairsA[(size_t)baseg[b] + (k - lstart[b])] = staged[i];
    }
}

// ===========================================================================
// pass 2: one block per bucket, LDS row cursors; writes confined to the
// bucket's ~47KB window -> L2-local
// ===========================================================================
__global__ __launch_bounds__(512) void fine_pass2(const ull* __restrict__ pairsA,
                                                  const int* __restrict__ rowStart,
                                                  ull* __restrict__ pairs) {
    __shared__ int cur[RPB + 1];
    const int b = blockIdx.x, t = threadIdx.x;
    const int r0 = b * RPB;
    const int nr = min(RPB, N_TOT - r0);
    for (int i = t; i <= nr; i += 512) cur[i] = rowStart[r0 + i];
    __syncthreads();
    const int s0 = cur[0];
    const int e0 = cur[nr];
    __syncthreads();                       // all read s0/e0 before cursors move
    for (int j = s0 + t; j < e0; j += 512) {
        ull e = pairsA[j];
        int rLow = (int)((e >> 19) & (RPB - 1));
        int pos = atomicAdd(&cur[rLow], 1);
        pairs[pos] = (e & 0xFFFFFFFF00000000ull) | (e & 0x7FFFFull);
    }
}

// ===========================================================================
// spmm_w: quarter-wave per destination row; aggregate RAW rows, then apply
// W in epilogue (linearity), leaky, l2norm.
//   LAYER 1: gather f32 from input embeddings;
//            tmp12 = bf16(emb[row] + n1); B2 = bf16(lv1). No f32 out write.
//   LAYER 2: gather bf16 from B2; out = f32(tmp12) + n2  (write-only out)
// ===========================================================================
template <int LAYER>
__global__ __launch_bounds__(256) void spmm_w(const ull* __restrict__ pairs,
                                              const int* __restrict__ rowStart,
                                              const float* __restrict__ u,
                                              const float* __restrict__ it,
                                              const unsigned short* __restrict__ B2in,
                                              unsigned short* __restrict__ B2out,
                                              const unsigned short* __restrict__ tmp12,
                                              unsigned short* __restrict__ tmp12out,
                                              const float* __restrict__ Wui,
                                              const float* __restrict__ Wsoc,
                                              float* __restrict__ out_ui,
                                              float* __restrict__ out_s,
                                              int uiBlocks) {
    __shared__ float Wsm[N_HID * N_HID];
    __shared__ float smX[4][4 * SMSTR];
    const int tid = threadIdx.x;
    const bool isUI = (int)blockIdx.x < uiBlocks;
    const int bl    = isUI ? blockIdx.x : blockIdx.x - uiBlocks;
    const int rbeg  = isUI ? bl * BR : N_NODES + bl * BR;
    const int rlim  = isUI ? min(BR, N_NODES - bl * BR) : min(BR, N_USER - bl * BR);

    const float* W = isUI ? Wui : Wsoc;
#pragma unroll
    for (int c = 0; c < 4; ++c)
        *(float4*)&Wsm[c * 1024 + tid * 4] = *(const float4*)&W[c * 1024 + tid * 4];
    __syncthreads();

    const int w  = tid >> 6;
    const int q  = (tid >> 4) & 3;
    const int l4 = (tid & 15) * 4;
    float* smx = &smX[w][q * SMSTR];

    for (int i = 0; i < 4; ++i) {
        int row = rbeg + w * 16 + i * 4 + q;
        if (row >= rbeg + rlim) continue;
        int s = rowStart[row];
        int e = rowStart[row + 1];
        float4 acc = make_float4(0.f, 0.f, 0.f, 0.f);
        for (int j = s; j < e; j += 8) {
            int last = e - 1;
            ull p[8]; float4 g[8]; float vv[8];
#pragma unroll
            for (int k = 0; k < 8; ++k) p[k] = pairs[min(j + k, last)];
#pragma unroll
            for (int k = 0; k < 8; ++k) {
                unsigned c = (unsigned)p[k] & 0x7FFFFu;
                if (LAYER == 1) {
                    const float* src =
                          (c < N_USER)  ? u  + (size_t)c * N_HID
                        : (c < N_NODES) ? it + (size_t)(c - N_USER) * N_HID
                                        : u  + (size_t)(c - N_NODES) * N_HID;
                    g[k] = *(const float4*)(src + l4);
                } else {
                    ushort4 s4 = *(const ushort4*)(B2in + (size_t)c * N_HID + l4);
                    g[k].x = bf_to_f(s4.x); g[k].y = bf_to_f(s4.y);
                    g[k].z = bf_to_f(s4.z); g[k].w = bf_to_f(s4.w);
                }
            }
#pragma unroll
            for (int k = 0; k < 8; ++k)
                vv[k] = (j + k < e) ? __uint_as_float((unsigned)(p[k] >> 32)) : 0.f;
#pragma unroll
            for (int k = 0; k < 8; ++k) {
                acc.x = fmaf(vv[k], g[k].x, acc.x);
                acc.y = fmaf(vv[k], g[k].y, acc.y);
                acc.z = fmaf(vv[k], g[k].z, acc.z);
                acc.w = fmaf(vv[k], g[k].w, acc.w);
            }
        }

        // stage aggregated row, apply W (z = agg @ W)
        *(float4*)&smx[l4] = acc;
        asm volatile("s_waitcnt lgkmcnt(0)" ::: "memory");
        float4 z = make_float4(0.f, 0.f, 0.f, 0.f);
#pragma unroll
        for (int k4 = 0; k4 < 16; ++k4) {
            float4 x4 = *(const float4*)&smx[k4 * 4];
            const float* wr = &Wsm[(k4 * 4) * N_HID + l4];
            float4 w0 = *(const float4*)(wr);
            float4 w1 = *(const float4*)(wr + N_HID);
            float4 w2 = *(const float4*)(wr + 2 * N_HID);
            float4 w3 = *(const float4*)(wr + 3 * N_HID);
            z.x = fmaf(x4.x, w0.x, z.x); z.x = fmaf(x4.y, w1.x, z.x);
            z.x = fmaf(x4.z, w2.x, z.x); z.x = fmaf(x4.w, w3.x, z.x);
            z.y = fmaf(x4.x, w0.y, z.y); z.y = fmaf(x4.y, w1.y, z.y);
            z.y = fmaf(x4.z, w2.y, z.y); z.y = fmaf(x4.w, w3.y, z.y);
            z.z = fmaf(x4.x, w0.z, z.z); z.z = fmaf(x4.y, w1.z, z.z);
            z.z = fmaf(x4.z, w2.z, z.z); z.z = fmaf(x4.w, w3.z, z.z);
            z.w = fmaf(x4.x, w0.w, z.w); z.w = fmaf(x4.y, w1.w, z.w);
            z.w = fmaf(x4.z, w2.w, z.w); z.w = fmaf(x4.w, w3.w, z.w);
        }

        float4 lv;
        lv.x = (z.x >= 0.f) ? z.x : 0.5f * z.x;
        lv.y = (z.y >= 0.f) ? z.y : 0.5f * z.y;
        lv.z = (z.z >= 0.f) ? z.z : 0.5f * z.z;
        lv.w = (z.w >= 0.f) ? z.w : 0.5f * z.w;
        float ss = lv.x * lv.x + lv.y * lv.y + lv.z * lv.z + lv.w * lv.w;
        ss += __shfl_xor(ss, 1, 64);
        ss += __shfl_xor(ss, 2, 64);
        ss += __shfl_xor(ss, 4, 64);
        ss += __shfl_xor(ss, 8, 64);
        float inv = 1.f / fmaxf(sqrtf(ss), 1e-12f);

        if (LAYER == 1) {
            const float* erow = isUI
                ? ((row < N_USER) ? u + (size_t)row * N_HID
                                  : it + (size_t)(row - N_USER) * N_HID)
                : u + (size_t)(row - N_NODES) * N_HID;
            float4 e4 = *(const float4*)&erow[l4];
            ushort4 t4, b4;
            t4.x = f_to_bf(fmaf(lv.x, inv, e4.x));
            t4.y = f_to_bf(fmaf(lv.y, inv, e4.y));
            t4.z = f_to_bf(fmaf(lv.z, inv, e4.z));
            t4.w = f_to_bf(fmaf(lv.w, inv, e4.w));
            b4.x = f_to_bf(lv.x); b4.y = f_to_bf(lv.y);
            b4.z = f_to_bf(lv.z); b4.w = f_to_bf(lv.w);
            *(ushort4*)(tmp12out + (size_t)row * N_HID + l4) = t4;
            *(ushort4*)(B2out   + (size_t)row * N_HID + l4) = b4;
        } else {
            float* op = isUI ? out_ui + (size_t)row * N_HID
                             : out_s  + (size_t)(row - N_NODES) * N_HID;
            ushort4 t4 = *(const ushort4*)(tmp12 + (size_t)row * N_HID + l4);
            float4 o;
            o.x = fmaf(lv.x, inv, bf_to_f(t4.x));
            o.y = fmaf(lv.y, inv, bf_to_f(t4.y));
            o.z = fmaf(lv.z, inv, bf_to_f(t4.z));
            o.w = fmaf(lv.w, inv, bf_to_f(t4.w));
            *(float4*)&op[l4] = o;
        }
    }
}

// ===========================================================================
// Atomic fallback (only if ws too small for the sorted path)
// ===========================================================================
__global__ __launch_bounds__(256) void init_concat(const float* __restrict__ u,
                                                   const float* __restrict__ it,
                                                   float* __restrict__ A,
                                                   float* __restrict__ out) {
    int i = blockIdx.x * 256 + threadIdx.x;
    const int nu4 = N_USER * N_HID / 4;
    const int nt4 = N_NODES * N_HID / 4;
    if (i >= nt4) return;
    float4 v = (i < nu4) ? ((const float4*)u)[i] : ((const float4*)it)[i - nu4];
    ((float4*)A)[i]   = v;
    ((float4*)out)[i] = v;
}

__global__ __launch_bounds__(256) void copy2(const float* __restrict__ src,
                                             float* __restrict__ d0,
                                             float* __restrict__ d1, int n4) {
    int i = blockIdx.x * 256 + threadIdx.x;
    if (i >= n4) return;
    float4 v = ((const float4*)src)[i];
    ((float4*)d0)[i] = v;
    ((float4*)d1)[i] = v;
}

__global__ __launch_bounds__(256) void gemm64(const float* __restrict__ X,
                                              const float* __restrict__ W,
                                              float* __restrict__ Y, int nrows) {
    __shared__ float Ws[N_HID * N_HID];
    int tid = threadIdx.x;
#pragma unroll
    for (int c = 0; c < 16; ++c) Ws[c * 256 + tid] = W[c * 256 + tid];
    __syncthreads();
    int row = blockIdx.x * 256 + tid;
    if (row >= nrows) return;
    float x[N_HID];
    const float4* xr = (const float4*)(X + (size_t)row * N_HID);
#pragma unroll
    for (int c = 0; c < 16; ++c) {
        float4 v = xr[c];
        x[4*c+0] = v.x; x[4*c+1] = v.y; x[4*c+2] = v.z; x[4*c+3] = v.w;
    }
    float4* y4 = (float4*)(Y + (size_t)row * N_HID);
    for (int jc = 0; jc < 16; ++jc) {
        float4 a = make_float4(0.f,0.f,0.f,0.f);
#pragma unroll
        for (int k = 0; k < N_HID; ++k) {
            float4 wv = *((const float4*)&Ws[k * N_HID + jc * 4]);
            a.x += x[k]*wv.x; a.y += x[k]*wv.y; a.z += x[k]*wv.z; a.w += x[k]*wv.w;
        }
        y4[jc] = a;
    }
}

__global__ __launch_bounds__(256) void spmm_scatter(const int* __restrict__ rows,
                                                    const int* __restrict__ cols,
                                                    const float* __restrict__ vals,
                                                    const float* __restrict__ X,
                                                    float* __restrict__ Y, int nedges) {
    long long t = (long long)blockIdx.x * 256 + threadIdx.x;
    int e = (int)(t >> 6);
    int h = (int)(t & 63);
    if (e >= nedges) return;
    atomicAdd(&Y[rows[e] * N_HID + h], vals[e] * X[cols[e] * N_HID + h]);
}

__global__ __launch_bounds__(256) void leaky_norm_acc(float* __restrict__ Y,
                                                      float* __restrict__ out, int nrows) {
    int row = blockIdx.x * 4 + (threadIdx.x >> 6);
    int h   = threadIdx.x & 63;
    if (row >= nrows) return;
    int idx = row * N_HID + h;
    float v = Y[idx];
    v = (v >= 0.f) ? v : 0.5f * v;
    Y[idx] = v;
    float s = v * v;
#pragma unroll
    for (int off = 32; off > 0; off >>= 1) s += __shfl_xor(s, off, 64);
    out[idx] += v / fmaxf(sqrtf(s), 1e-12f);
}

// ===========================================================================
extern "C" void kernel_launch(void* const* d_in, const int* in_sizes, int n_in,
                              void* d_out, int out_size, void* d_ws, size_t ws_size,
                              hipStream_t stream) {
    const float* user_emb = (const float*)d_in[0];
    const float* item_emb = (const float*)d_in[1];
    const float* ui_w     = (const float*)d_in[2];
    const float* s_w      = (const float*)d_in[3];
    const int*   ui_rows  = (const int*)d_in[4];
    const int*   ui_cols  = (const int*)d_in[5];
    const float* ui_vals  = (const float*)d_in[6];
    const int*   s_rows   = (const int*)d_in[7];
    const int*   s_cols   = (const int*)d_in[8];
    const float* s_vals   = (const float*)d_in[9];

    float* out_ui = (float*)d_out;
    float* out_s  = (float*)d_out + (size_t)N_NODES * N_HID;

    const size_t szUI    = (size_t)N_NODES * N_HID * sizeof(float);      // 64.0 MB
    const size_t szBF    = (size_t)N_TOT * N_HID * sizeof(short);        // 44.8 MB
    const size_t rsPad   = 1400832;                                      // (N_TOT+1)*4 padded

    const int uiBlocks = (N_NODES + BR - 1) / BR;    // 3907
    const int sBlocks  = (N_USER  + BR - 1) / BR;    // 1563
    const int nbScan   = (N_TOT + 511) / 512;        // 684
    const int nbE      = (E_TOT + 255) / 256;
    const int nbP1     = (E_TOT + CH - 1) / CH;      // 489

    const size_t needBytes = 2 * szBF + (size_t)E_TOT * 8 + rsPad + 8192 + 8192; // ~107 MB

    if (ws_size >= needBytes) {
        unsigned short* B2    = (unsigned short*)d_ws;                   // lv1 (bf16)
        unsigned short* tmp12 = (unsigned short*)((char*)d_ws + szBF);   // emb+n1 (bf16)
        char* p = (char*)d_ws + 2 * szBF;
        ull* pairs     = (ull*)p;            p += (size_t)E_TOT * 8;
        int* rowStart  = (int*)p;            p += rsPad;
        int* blockSums = (int*)p;            p += 8192;
        int* bucketCur = (int*)p;
        ull* pairsA    = (ull*)tmp12;        // sort staging aliases tmp12 (dead until L1 epi)

        // ---- sort: hist -> scan -> LDS-binned coarse scatter -> L2-local fine scatter
        hipMemsetAsync(rowStart, 0, (size_t)N_TOT * 4, stream);
        edge_hist2<<<nbE, 256, 0, stream>>>(ui_rows, s_rows, rowStart);
        scan_block512<<<nbScan, 256, 0, stream>>>(rowStart, blockSums, N_TOT);
        scan_sums<<<1, 1024, 0, stream>>>(blockSums, nbScan);
        scan_add512<<<nbScan, 256, 0, stream>>>(rowStart, blockSums, bucketCur,
                                                N_TOT, E_TOT);
        bin_pass1<<<nbP1, 256, 0, stream>>>(ui_rows, ui_cols, ui_vals,
                                            s_rows, s_cols, s_vals, bucketCur, pairsA);
        fine_pass2<<<NBKT, 512, 0, stream>>>(pairsA, rowStart, pairs);

        // ---- 2 fused spmm dispatches
        const int grid = uiBlocks + sBlocks;
        spmm_w<1><<<grid, 256, 0, stream>>>(pairs, rowStart, user_emb, item_emb,
                                            nullptr, B2, nullptr, tmp12,
                                            ui_w, s_w, out_ui, out_s, uiBlocks);
        spmm_w<2><<<grid, 256, 0, stream>>>(pairs, rowStart, user_emb, item_emb,
                                            B2, nullptr, tmp12, nullptr,
                                            ui_w + N_HID * N_HID, s_w + N_HID * N_HID,
                                            out_ui, out_s, uiBlocks);
        return;
    }

    // ------------------- fallback: atomic path -------------------
    float* A = (float*)d_ws;
    float* B = (float*)((char*)d_ws + szUI);
    init_concat<<<(N_NODES * N_HID / 4 + 255) / 256, 256, 0, stream>>>(
        user_emb, item_emb, A, out_ui);
    for (int l = 0; l < 2; ++l) {
        gemm64<<<(N_NODES + 255) / 256, 256, 0, stream>>>(
            A, ui_w + l * N_HID * N_HID, B, N_NODES);
        hipMemsetAsync(A, 0, szUI, stream);
        spmm_scatter<<<(int)(((long long)E_UI * 64) / 256), 256, 0, stream>>>(
            ui_rows, ui_cols, ui_vals, B, A, E_UI);
        leaky_norm_acc<<<(N_NODES + 3) / 4, 256, 0, stream>>>(A, out_ui, N_NODES);
    }
    copy2<<<(N_USER * N_HID / 4 + 255) / 256, 256, 0, stream>>>(
        user_emb, A, out_s, N_USER * N_HID / 4);
    const size_t sBytes = (size_t)N_USER * N_HID * sizeof(float);
    for (int l = 0; l < 2; ++l) {
        gemm64<<<(N_USER + 255) / 256, 256, 0, stream>>>(
            A, s_w + l * N_HID * N_HID, B, N_USER);
        hipMemsetAsync(A, 0, sBytes, stream);
        spmm_scatter<<<(int)(((long long)E_S * 64) / 256), 256, 0, stream>>>(
            s_rows, s_cols, s_vals, B, A, E_S);
        leaky_norm_acc<<<(N_USER + 3) / 4, 256, 0, stream>>>(A, out_s, N_USER);
    }
}

// Round 8
// 321.304 us; speedup vs baseline: 1.4917x; 1.0809x over previous
//
#include <hip/hip_runtime.h>

#define N_USER   100000
#define N_ITEM   150000
#define N_NODES  250000
#define N_HID    64
#define E_UI     1000000
#define E_S      1000000
#define N_TOT    (N_NODES + N_USER)      // 350000
#define E_TOT    (E_UI + E_S)            // 2000000

#define BR     64                         // rows per block (spmm)
#define CH     4096                       // edges per bin_pass1 chunk
#define RPB    1024                       // rows per coarse bucket
#define RPB_SH 10
#define NBKT   ((N_TOT + RPB - 1) / RPB)  // 342
#define NBKTP  512                        // padded bucket-array size
#define ASTR   72                         // agg LDS row stride (shorts, 144B)

typedef unsigned long long ull;
typedef __attribute__((ext_vector_type(8))) short short8v;   // 8 bf16 (4 VGPR)
typedef __attribute__((ext_vector_type(4))) float f32x4;

__device__ __forceinline__ unsigned short f_to_bf(float f) {
    unsigned u = __float_as_uint(f);
    u += 0x7FFF + ((u >> 16) & 1);
    return (unsigned short)(u >> 16);
}
__device__ __forceinline__ float bf_to_f(unsigned short s) {
    return __uint_as_float((unsigned)s << 16);
}
__device__ __forceinline__ unsigned pack_bf2(float a, float b) {
    return (unsigned)f_to_bf(a) | ((unsigned)f_to_bf(b) << 16);
}

// ===========================================================================
// prepass: bf16 cast of concat(user,item) -> embBf[250K][64]
// ===========================================================================
__global__ __launch_bounds__(256) void embcast(const float* __restrict__ u,
                                               const float* __restrict__ it,
                                               unsigned short* __restrict__ embBf) {
    int i = blockIdx.x * 256 + threadIdx.x;            // 8 elems per thread
    const int n8 = N_NODES * N_HID / 8;
    if (i >= n8) return;
    size_t base = (size_t)i * 8;
    const size_t nu = (size_t)N_USER * N_HID;
    const float* src = (base < nu) ? u + base : it + (base - nu);
    float4 a = *(const float4*)src;
    float4 b = *(const float4*)(src + 4);
    uint4 o;
    o.x = pack_bf2(a.x, a.y); o.y = pack_bf2(a.z, a.w);
    o.z = pack_bf2(b.x, b.y); o.w = pack_bf2(b.z, b.w);
    *(uint4*)&embBf[base] = o;
}

// ===========================================================================
// histogram + scan (CSR rowStart over combined 350K rows)
// ===========================================================================
__global__ __launch_bounds__(256) void edge_hist2(const int* __restrict__ ui_rows,
                                                  const int* __restrict__ s_rows,
                                                  int* __restrict__ counts) {
    int i = blockIdx.x * 256 + threadIdx.x;
    if (i < E_UI)            atomicAdd(&counts[ui_rows[i]], 1);
    else if (i < E_TOT)      atomicAdd(&counts[N_NODES + s_rows[i - E_UI]], 1);
}

__global__ __launch_bounds__(256) void scan_block512(int* __restrict__ data,
                                                     int* __restrict__ blockSums, int n) {
    __shared__ int sm[512];
    int t = threadIdx.x;
    int base = blockIdx.x * 512;
    int i0 = base + t, i1 = base + t + 256;
    int v0 = (i0 < n) ? data[i0] : 0;
    int v1 = (i1 < n) ? data[i1] : 0;
    sm[t] = v0; sm[t + 256] = v1;
    __syncthreads();
    for (int off = 1; off < 512; off <<= 1) {
        int a = (t >= off) ? sm[t - off] : 0;
        int b = (t + 256 >= off) ? sm[t + 256 - off] : 0;
        __syncthreads();
        sm[t] += a; sm[t + 256] += b;
        __syncthreads();
    }
    if (i0 < n) data[i0] = sm[t] - v0;
    if (i1 < n) data[i1] = sm[t + 256] - v1;
    if (t == 255) blockSums[blockIdx.x] = sm[511];
}

__global__ __launch_bounds__(1024) void scan_sums(int* __restrict__ blockSums, int nb) {
    __shared__ int sm[1024];
    int v = (threadIdx.x < nb) ? blockSums[threadIdx.x] : 0;
    sm[threadIdx.x] = v;
    __syncthreads();
    for (int off = 1; off < 1024; off <<= 1) {
        int t = (threadIdx.x >= off) ? sm[threadIdx.x - off] : 0;
        __syncthreads();
        sm[threadIdx.x] += t;
        __syncthreads();
    }
    if (threadIdx.x < nb) blockSums[threadIdx.x] = sm[threadIdx.x] - v;
}

__global__ __launch_bounds__(256) void scan_add512(int* __restrict__ data,
                                                   const int* __restrict__ blockSums,
                                                   int* __restrict__ bucketCur,
                                                   int n, int total) {
    int base = blockIdx.x * 512;
    int s = blockSums[blockIdx.x];
#pragma unroll
    for (int k = 0; k < 2; ++k) {
        int i = base + threadIdx.x + k * 256;
        if (i < n) {
            int v = data[i] + s;
            data[i] = v;
            if ((i & (RPB - 1)) == 0) bucketCur[i >> RPB_SH] = v;
        }
    }
    if (blockIdx.x == 0 && threadIdx.x == 0) data[n] = total;
}

// ===========================================================================
// pass 1: LDS binning by coarse bucket; coalesced bucket-run writes to pairsA
//   entry = v<<32 | rLow<<19 | c
// ===========================================================================
__global__ __launch_bounds__(256) void bin_pass1(const int* __restrict__ ui_rows,
                                                 const int* __restrict__ ui_cols,
                                                 const float* __restrict__ ui_vals,
                                                 const int* __restrict__ s_rows,
                                                 const int* __restrict__ s_cols,
                                                 const float* __restrict__ s_vals,
                                                 int* __restrict__ bucketCur,
                                                 ull* __restrict__ pairsA) {
    __shared__ ull            staged[CH];
    __shared__ unsigned short bkt[CH];
    __shared__ unsigned short ord[CH];
    __shared__ int hist[NBKTP];
    __shared__ int lstart[NBKTP];
    __shared__ int cnt2[NBKTP];
    __shared__ int baseg[NBKTP];
    const int t = threadIdx.x;
    hist[t] = 0; hist[t + 256] = 0;
    cnt2[t] = 0; cnt2[t + 256] = 0;
    __syncthreads();

    const int e0 = blockIdx.x * CH;
    const int n  = min(CH, E_TOT - e0);

    for (int i = t; i < n; i += 256) {
        int g = e0 + i, r, c; float v;
        if (g < E_UI) { r = ui_rows[g];            c = ui_cols[g];            v = ui_vals[g]; }
        else          { int k = g - E_UI;
                        r = N_NODES + s_rows[k];   c = N_NODES + s_cols[k];   v = s_vals[k]; }
        int b = r >> RPB_SH;
        staged[i] = ((ull)__float_as_uint(v) << 32) |
                    ((ull)(unsigned)(r & (RPB - 1)) << 19) | (unsigned)c;
        bkt[i] = (unsigned short)b;
        atomicAdd(&hist[b], 1);
    }
    __syncthreads();

    int v0 = hist[t], v1 = hist[t + 256];
    lstart[t] = v0; lstart[t + 256] = v1;
    __syncthreads();
    for (int off = 1; off < NBKTP; off <<= 1) {
        int a = (t >= off) ? lstart[t - off] : 0;
        int b = (t + 256 >= off) ? lstart[t + 256 - off] : 0;
        __syncthreads();
        lstart[t] += a; lstart[t + 256] += b;
        __syncthreads();
    }
    int ex0 = lstart[t] - v0, ex1 = lstart[t + 256] - v1;
    __syncthreads();
    lstart[t] = ex0; lstart[t + 256] = ex1;
    if (v0 > 0) baseg[t] = atomicAdd(&bucketCur[t], v0);
    if (v1 > 0) baseg[t + 256] = atomicAdd(&bucketCur[t + 256], v1);
    __syncthreads();

    for (int i = t; i < n; i += 256) {
        int b = bkt[i];
        int l = atomicAdd(&cnt2[b], 1);
        ord[lstart[b] + l] = (unsigned short)i;
    }
    __syncthreads();

    for (int k = t; k < n; k += 256) {
        int i = ord[k];
        int b = bkt[i];
        pairsA[(size_t)baseg[b] + (k - lstart[b])] = staged[i];
    }
}

// ===========================================================================
// pass 2: one block per bucket, LDS row cursors; writes L2-local
// ===========================================================================
__global__ __launch_bounds__(512) void fine_pass2(const ull* __restrict__ pairsA,
                                                  const int* __restrict__ rowStart,
                                                  ull* __restrict__ pairs) {
    __shared__ int cur[RPB + 1];
    const int b = blockIdx.x, t = threadIdx.x;
    const int r0 = b * RPB;
    const int nr = min(RPB, N_TOT - r0);
    for (int i = t; i <= nr; i += 512) cur[i] = rowStart[r0 + i];
    __syncthreads();
    const int s0 = cur[0];
    const int e0 = cur[nr];
    __syncthreads();
    for (int j = s0 + t; j < e0; j += 512) {
        ull e = pairsA[j];
        int rLow = (int)((e >> 19) & (RPB - 1));
        int pos = atomicAdd(&cur[rLow], 1);
        pairs[pos] = (e & 0xFFFFFFFF00000000ull) | (e & 0x7FFFFull);
    }
}

// ===========================================================================
// spmm_m: quarter-wave gather (bf16 sources) + MFMA W-apply epilogue.
//   wave = 16 rows; agg staged bf16 in LDS; W preloaded as 8 B-frags (VGPR).
//   LAYER 1: gather embBf; tmp12 = bf16(emb+n1); B2 = bf16(lv1)
//   LAYER 2: gather B2;    out = f32(tmp12) + n2
// ===========================================================================
template <int LAYER>
__global__ __launch_bounds__(256) void spmm_m(const ull* __restrict__ pairs,
                                              const int* __restrict__ rowStart,
                                              const unsigned short* __restrict__ embBf,
                                              const unsigned short* __restrict__ B2in,
                                              unsigned short* __restrict__ B2out,
                                              const unsigned short* __restrict__ tmp12in,
                                              unsigned short* __restrict__ tmp12out,
                                              const float* __restrict__ Wui,
                                              const float* __restrict__ Wsoc,
                                              float* __restrict__ out_ui,
                                              float* __restrict__ out_s,
                                              int uiBlocks) {
    __shared__ unsigned short Wb[N_HID][ASTR];        // Wb[c][r] = bf16(W[r][c])
    __shared__ unsigned short agg[4][16][ASTR];       // per-wave 16 aggregated rows
    const int tid = threadIdx.x;
    const bool isUI = (int)blockIdx.x < uiBlocks;
    const int bl    = isUI ? blockIdx.x : blockIdx.x - uiBlocks;
    const int rbeg  = isUI ? bl * BR : N_NODES + bl * BR;
    const int rlim  = isUI ? min(BR, N_NODES - bl * BR) : min(BR, N_USER - bl * BR);

    // stage W transposed as bf16 (once per block)
    const float* W = isUI ? Wui : Wsoc;
    for (int idx = tid; idx < N_HID * N_HID; idx += 256) {
        int r = idx >> 6, c = idx & 63;
        Wb[c][r] = f_to_bf(W[idx]);
    }
    __syncthreads();

    const int w = tid >> 6;                 // wave id (16 rows each)
    if (w * 16 >= rlim) return;             // rlim is always a multiple of 16
    const int s = tid & 15;                 // lane-in-quarter / MFMA row-col id
    const int g = (tid >> 4) & 3;           // quarter / MFMA k-group

    // preload W B-fragments: b[nt][kt] = W[kt*32+g*8+j][nt*16+s]
    short8v bfrag[4][2];
#pragma unroll
    for (int nt = 0; nt < 4; ++nt)
#pragma unroll
        for (int kt = 0; kt < 2; ++kt)
            bfrag[nt][kt] = *(const short8v*)&Wb[nt * 16 + s][kt * 32 + g * 8];

    const unsigned short* gsrc = (LAYER == 1) ? embBf : B2in;

    // ---- gather: 4 iters, quarter q=g handles row i*4+g; stage bf16 agg ----
    for (int i = 0; i < 4; ++i) {
        int m = i * 4 + g;
        int row = rbeg + w * 16 + m;
        int sB = rowStart[row];
        int eB = rowStart[row + 1];
        float4 acc = make_float4(0.f, 0.f, 0.f, 0.f);
        for (int j = sB; j < eB; j += 8) {
            int last = eB - 1;
            ull p[8]; float4 gg[8]; float vv[8];
#pragma unroll
            for (int k = 0; k < 8; ++k) p[k] = pairs[min(j + k, last)];
#pragma unroll
            for (int k = 0; k < 8; ++k) {
                unsigned c = (unsigned)p[k] & 0x7FFFFu;
                if (LAYER == 1 && c >= N_NODES) c -= N_NODES;
                ushort4 s4 = *(const ushort4*)(gsrc + (size_t)c * N_HID + s * 4);
                gg[k].x = bf_to_f(s4.x); gg[k].y = bf_to_f(s4.y);
                gg[k].z = bf_to_f(s4.z); gg[k].w = bf_to_f(s4.w);
            }
#pragma unroll
            for (int k = 0; k < 8; ++k)
                vv[k] = (j + k < eB) ? __uint_as_float((unsigned)(p[k] >> 32)) : 0.f;
#pragma unroll
            for (int k = 0; k < 8; ++k) {
                acc.x = fmaf(vv[k], gg[k].x, acc.x);
                acc.y = fmaf(vv[k], gg[k].y, acc.y);
                acc.z = fmaf(vv[k], gg[k].z, acc.z);
                acc.w = fmaf(vv[k], gg[k].w, acc.w);
            }
        }
        uint2 pk;
        pk.x = pack_bf2(acc.x, acc.y);
        pk.y = pack_bf2(acc.z, acc.w);
        *(uint2*)&agg[w][m][s * 4] = pk;
    }
    asm volatile("s_waitcnt lgkmcnt(0)" ::: "memory");
    __builtin_amdgcn_sched_barrier(0);

    // ---- MFMA: z(16x64) = agg(16x64) @ W(64x64) ----
    short8v a0 = *(const short8v*)&agg[w][s][g * 8];        // kt=0
    short8v a1 = *(const short8v*)&agg[w][s][32 + g * 8];   // kt=1
    f32x4 c[4];
    const f32x4 zero4 = {0.f, 0.f, 0.f, 0.f};
#pragma unroll
    for (int nt = 0; nt < 4; ++nt) {
        c[nt] = __builtin_amdgcn_mfma_f32_16x16x32_bf16(a0, bfrag[nt][0], zero4, 0, 0, 0);
        c[nt] = __builtin_amdgcn_mfma_f32_16x16x32_bf16(a1, bfrag[nt][1], c[nt], 0, 0, 0);
    }

    // ---- leaky + row l2norm (C/D: col = nt*16+s, row = g*4+r) ----
    float lv[4][4];                                   // [nt][r]
    float ss[4] = {0.f, 0.f, 0.f, 0.f};
#pragma unroll
    for (int nt = 0; nt < 4; ++nt)
#pragma unroll
        for (int r = 0; r < 4; ++r) {
            float z = c[nt][r];
            float l = (z >= 0.f) ? z : 0.5f * z;
            lv[nt][r] = l;
            ss[r] = fmaf(l, l, ss[r]);
        }
#pragma unroll
    for (int r = 0; r < 4; ++r) {
        float t = ss[r];
        t += __shfl_xor(t, 1, 64);
        t += __shfl_xor(t, 2, 64);
        t += __shfl_xor(t, 4, 64);
        t += __shfl_xor(t, 8, 64);
        ss[r] = 1.f / fmaxf(sqrtf(t), 1e-12f);
    }

    // ---- outputs ----
#pragma unroll
    for (int r = 0; r < 4; ++r) {
        int R = rbeg + w * 16 + g * 4 + r;
        if (LAYER == 1) {
            size_t eRow = isUI ? (size_t)R : (size_t)(R - N_NODES);
#pragma unroll
            for (int nt = 0; nt < 4; ++nt) {
                int col = nt * 16 + s;
                float eb = bf_to_f(embBf[eRow * N_HID + col]);
                tmp12out[(size_t)R * N_HID + col] = f_to_bf(fmaf(lv[nt][r], ss[r], eb));
                B2out[(size_t)R * N_HID + col]    = f_to_bf(lv[nt][r]);
            }
        } else {
            float* op = isUI ? out_ui + (size_t)R * N_HID
                             : out_s  + (size_t)(R - N_NODES) * N_HID;
#pragma unroll
            for (int nt = 0; nt < 4; ++nt) {
                int col = nt * 16 + s;
                float tb = bf_to_f(tmp12in[(size_t)R * N_HID + col]);
                op[col] = fmaf(lv[nt][r], ss[r], tb);
            }
        }
    }
}

// ===========================================================================
// Atomic fallback (only if ws too small for the sorted path)
// ===========================================================================
__global__ __launch_bounds__(256) void init_concat(const float* __restrict__ u,
                                                   const float* __restrict__ it,
                                                   float* __restrict__ A,
                                                   float* __restrict__ out) {
    int i = blockIdx.x * 256 + threadIdx.x;
    const int nu4 = N_USER * N_HID / 4;
    const int nt4 = N_NODES * N_HID / 4;
    if (i >= nt4) return;
    float4 v = (i < nu4) ? ((const float4*)u)[i] : ((const float4*)it)[i - nu4];
    ((float4*)A)[i]   = v;
    ((float4*)out)[i] = v;
}

__global__ __launch_bounds__(256) void copy2(const float* __restrict__ src,
                                             float* __restrict__ d0,
                                             float* __restrict__ d1, int n4) {
    int i = blockIdx.x * 256 + threadIdx.x;
    if (i >= n4) return;
    float4 v = ((const float4*)src)[i];
    ((float4*)d0)[i] = v;
    ((float4*)d1)[i] = v;
}

__global__ __launch_bounds__(256) void gemm64(const float* __restrict__ X,
                                              const float* __restrict__ W,
                                              float* __restrict__ Y, int nrows) {
    __shared__ float Ws[N_HID * N_HID];
    int tid = threadIdx.x;
#pragma unroll
    for (int c = 0; c < 16; ++c) Ws[c * 256 + tid] = W[c * 256 + tid];
    __syncthreads();
    int row = blockIdx.x * 256 + tid;
    if (row >= nrows) return;
    float x[N_HID];
    const float4* xr = (const float4*)(X + (size_t)row * N_HID);
#pragma unroll
    for (int c = 0; c < 16; ++c) {
        float4 v = xr[c];
        x[4*c+0] = v.x; x[4*c+1] = v.y; x[4*c+2] = v.z; x[4*c+3] = v.w;
    }
    float4* y4 = (float4*)(Y + (size_t)row * N_HID);
    for (int jc = 0; jc < 16; ++jc) {
        float4 a = make_float4(0.f,0.f,0.f,0.f);
#pragma unroll
        for (int k = 0; k < N_HID; ++k) {
            float4 wv = *((const float4*)&Ws[k * N_HID + jc * 4]);
            a.x += x[k]*wv.x; a.y += x[k]*wv.y; a.z += x[k]*wv.z; a.w += x[k]*wv.w;
        }
        y4[jc] = a;
    }
}

__global__ __launch_bounds__(256) void spmm_scatter(const int* __restrict__ rows,
                                                    const int* __restrict__ cols,
                                                    const float* __restrict__ vals,
                                                    const float* __restrict__ X,
                                                    float* __restrict__ Y, int nedges) {
    long long t = (long long)blockIdx.x * 256 + threadIdx.x;
    int e = (int)(t >> 6);
    int h = (int)(t & 63);
    if (e >= nedges) return;
    atomicAdd(&Y[rows[e] * N_HID + h], vals[e] * X[cols[e] * N_HID + h]);
}

__global__ __launch_bounds__(256) void leaky_norm_acc(float* __restrict__ Y,
                                                      float* __restrict__ out, int nrows) {
    int row = blockIdx.x * 4 + (threadIdx.x >> 6);
    int h   = threadIdx.x & 63;
    if (row >= nrows) return;
    int idx = row * N_HID + h;
    float v = Y[idx];
    v = (v >= 0.f) ? v : 0.5f * v;
    Y[idx] = v;
    float s = v * v;
#pragma unroll
    for (int off = 32; off > 0; off >>= 1) s += __shfl_xor(s, off, 64);
    out[idx] += v / fmaxf(sqrtf(s), 1e-12f);
}

// ===========================================================================
extern "C" void kernel_launch(void* const* d_in, const int* in_sizes, int n_in,
                              void* d_out, int out_size, void* d_ws, size_t ws_size,
                              hipStream_t stream) {
    const float* user_emb = (const float*)d_in[0];
    const float* item_emb = (const float*)d_in[1];
    const float* ui_w     = (const float*)d_in[2];
    const float* s_w      = (const float*)d_in[3];
    const int*   ui_rows  = (const int*)d_in[4];
    const int*   ui_cols  = (const int*)d_in[5];
    const float* ui_vals  = (const float*)d_in[6];
    const int*   s_rows   = (const int*)d_in[7];
    const int*   s_cols   = (const int*)d_in[8];
    const float* s_vals   = (const float*)d_in[9];

    float* out_ui = (float*)d_out;
    float* out_s  = (float*)d_out + (size_t)N_NODES * N_HID;

    const size_t szUI  = (size_t)N_NODES * N_HID * sizeof(float);     // 64.0 MB
    const size_t szEB  = (size_t)N_NODES * N_HID * sizeof(short);     // 32.0 MB
    const size_t szBF  = (size_t)N_TOT   * N_HID * sizeof(short);     // 44.8 MB
    const size_t rsPad = 1400832;

    const int uiBlocks = (N_NODES + BR - 1) / BR;    // 3907
    const int sBlocks  = (N_USER  + BR - 1) / BR;    // 1563
    const int nbScan   = (N_TOT + 511) / 512;
    const int nbE      = (E_TOT + 255) / 256;
    const int nbP1     = (E_TOT + CH - 1) / CH;
    const int nbEC     = (N_NODES * N_HID / 8 + 255) / 256;

    const size_t needBytes = szEB + 2 * szBF + (size_t)E_TOT * 8 + rsPad + 8192 + 8192;

    if (ws_size >= needBytes) {
        unsigned short* embBf = (unsigned short*)d_ws;
        unsigned short* B2    = (unsigned short*)((char*)d_ws + szEB);
        unsigned short* tmp12 = (unsigned short*)((char*)d_ws + szEB + szBF);
        char* p = (char*)d_ws + szEB + 2 * szBF;
        ull* pairs     = (ull*)p;            p += (size_t)E_TOT * 8;
        int* rowStart  = (int*)p;            p += rsPad;
        int* blockSums = (int*)p;            p += 8192;
        int* bucketCur = (int*)p;
        ull* pairsA    = (ull*)tmp12;        // staging aliases tmp12 (dead until L1 epi)

        // ---- prepass + sort ----
        embcast<<<nbEC, 256, 0, stream>>>(user_emb, item_emb, embBf);
        hipMemsetAsync(rowStart, 0, (size_t)N_TOT * 4, stream);
        edge_hist2<<<nbE, 256, 0, stream>>>(ui_rows, s_rows, rowStart);
        scan_block512<<<nbScan, 256, 0, stream>>>(rowStart, blockSums, N_TOT);
        scan_sums<<<1, 1024, 0, stream>>>(blockSums, nbScan);
        scan_add512<<<nbScan, 256, 0, stream>>>(rowStart, blockSums, bucketCur,
                                                N_TOT, E_TOT);
        bin_pass1<<<nbP1, 256, 0, stream>>>(ui_rows, ui_cols, ui_vals,
                                            s_rows, s_cols, s_vals, bucketCur, pairsA);
        fine_pass2<<<NBKT, 512, 0, stream>>>(pairsA, rowStart, pairs);

        // ---- 2 fused spmm dispatches (MFMA epilogue) ----
        const int grid = uiBlocks + sBlocks;
        spmm_m<1><<<grid, 256, 0, stream>>>(pairs, rowStart, embBf,
                                            nullptr, B2, nullptr, tmp12,
                                            ui_w, s_w, out_ui, out_s, uiBlocks);
        spmm_m<2><<<grid, 256, 0, stream>>>(pairs, rowStart, embBf,
                                            B2, nullptr, tmp12, nullptr,
                                            ui_w + N_HID * N_HID, s_w + N_HID * N_HID,
                                            out_ui, out_s, uiBlocks);
        return;
    }

    // ------------------- fallback: atomic path -------------------
    float* A = (float*)d_ws;
    float* B = (float*)((char*)d_ws + szUI);
    init_concat<<<(N_NODES * N_HID / 4 + 255) / 256, 256, 0, stream>>>(
        user_emb, item_emb, A, out_ui);
    for (int l = 0; l < 2; ++l) {
        gemm64<<<(N_NODES + 255) / 256, 256, 0, stream>>>(
            A, ui_w + l * N_HID * N_HID, B, N_NODES);
        hipMemsetAsync(A, 0, szUI, stream);
        spmm_scatter<<<(int)(((long long)E_UI * 64) / 256), 256, 0, stream>>>(
            ui_rows, ui_cols, ui_vals, B, A, E_UI);
        leaky_norm_acc<<<(N_NODES + 3) / 4, 256, 0, stream>>>(A, out_ui, N_NODES);
    }
    copy2<<<(N_USER * N_HID / 4 + 255) / 256, 256, 0, stream>>>(
        user_emb, A, out_s, N_USER * N_HID / 4);
    const size_t sBytes = (size_t)N_USER * N_HID * sizeof(float);
    for (int l = 0; l < 2; ++l) {
        gemm64<<<(N_USER + 255) / 256, 256, 0, stream>>>(
            A, s_w + l * N_HID * N_HID, B, N_USER);
        hipMemsetAsync(A, 0, sBytes, stream);
        spmm_scatter<<<(int)(((long long)E_S * 64) / 256), 256, 0, stream>>>(
            s_rows, s_cols, s_vals, B, A, E_S);
        leaky_norm_acc<<<(N_USER + 3) / 4, 256, 0, stream>>>(A, out_s, N_USER);
    }
}

// Round 9
// 309.594 us; speedup vs baseline: 1.5481x; 1.0378x over previous
//
#include <hip/hip_runtime.h>

#define N_USER   100000
#define N_ITEM   150000
#define N_NODES  250000
#define N_HID    64
#define E_UI     1000000
#define E_S      1000000
#define N_TOT    (N_NODES + N_USER)      // 350000
#define E_TOT    (E_UI + E_S)            // 2000000

#define BR     64                         // rows per block (spmm)
#define CH     4096                       // edges per binning chunk
#define RPB    1024                       // rows per coarse bucket
#define RPB_SH 10
#define NBKT   ((N_TOT + RPB - 1) / RPB)  // 342
#define NBKTP  512                        // padded bucket-array size
#define BSTR   12288                      // fixed pairsA stride per bucket
#define ASTR   72                         // agg LDS row stride (shorts, 144B)

typedef unsigned long long ull;
typedef __attribute__((ext_vector_type(8))) short short8v;   // 8 bf16 (4 VGPR)
typedef __attribute__((ext_vector_type(4))) float f32x4;

__device__ __forceinline__ unsigned short f_to_bf(float f) {
    unsigned u = __float_as_uint(f);
    u += 0x7FFF + ((u >> 16) & 1);
    return (unsigned short)(u >> 16);
}
__device__ __forceinline__ float bf_to_f(unsigned short s) {
    return __uint_as_float((unsigned)s << 16);
}
__device__ __forceinline__ unsigned pack_bf2(float a, float b) {
    return (unsigned)f_to_bf(a) | ((unsigned)f_to_bf(b) << 16);
}

// ===========================================================================
// seed fixed-stride bucket cursors
// ===========================================================================
__global__ __launch_bounds__(512) void seedk(int* __restrict__ bucketCur) {
    bucketCur[threadIdx.x] = (int)threadIdx.x * BSTR;
}

// ===========================================================================
// merged: [blocks 0..nbBin) LDS binning into fixed-stride pairsA + row hist
//         [blocks nbBin..)  bf16 cast of concat(user,item) -> embBf
//   entry = v<<32 | rLow<<19 | c
// ===========================================================================
__global__ __launch_bounds__(256) void bin_embcast(const int* __restrict__ ui_rows,
                                                   const int* __restrict__ ui_cols,
                                                   const float* __restrict__ ui_vals,
                                                   const int* __restrict__ s_rows,
                                                   const int* __restrict__ s_cols,
                                                   const float* __restrict__ s_vals,
                                                   int* __restrict__ bucketCur,
                                                   int* __restrict__ rowHist,
                                                   ull* __restrict__ pairsA,
                                                   const float* __restrict__ u,
                                                   const float* __restrict__ it,
                                                   unsigned short* __restrict__ embBf,
                                                   int nbBin) {
    __shared__ ull            staged[CH];
    __shared__ unsigned short bkt[CH];
    __shared__ unsigned short ord[CH];
    __shared__ int hist[NBKTP];
    __shared__ int lstart[NBKTP];
    __shared__ int cnt2[NBKTP];
    __shared__ int baseg[NBKTP];
    const int t = threadIdx.x;

    if ((int)blockIdx.x >= nbBin) {               // ---- embcast part ----
        int i = ((int)blockIdx.x - nbBin) * 256 + t;
        const int n8 = N_NODES * N_HID / 8;
        if (i >= n8) return;
        size_t base = (size_t)i * 8;
        const size_t nu = (size_t)N_USER * N_HID;
        const float* src = (base < nu) ? u + base : it + (base - nu);
        float4 a = *(const float4*)src;
        float4 b = *(const float4*)(src + 4);
        uint4 o;
        o.x = pack_bf2(a.x, a.y); o.y = pack_bf2(a.z, a.w);
        o.z = pack_bf2(b.x, b.y); o.w = pack_bf2(b.z, b.w);
        *(uint4*)&embBf[base] = o;
        return;
    }

    // ---- binning part ----
    hist[t] = 0; hist[t + 256] = 0;
    cnt2[t] = 0; cnt2[t + 256] = 0;
    __syncthreads();

    const int e0 = blockIdx.x * CH;
    const int n  = min(CH, E_TOT - e0);

    for (int i = t; i < n; i += 256) {
        int g = e0 + i, r, c; float v;
        if (g < E_UI) { r = ui_rows[g];            c = ui_cols[g];            v = ui_vals[g]; }
        else          { int k = g - E_UI;
                        r = N_NODES + s_rows[k];   c = N_NODES + s_cols[k];   v = s_vals[k]; }
        int b = r >> RPB_SH;
        staged[i] = ((ull)__float_as_uint(v) << 32) |
                    ((ull)(unsigned)(r & (RPB - 1)) << 19) | (unsigned)c;
        bkt[i] = (unsigned short)b;
        atomicAdd(&hist[b], 1);
        atomicAdd(&rowHist[r], 1);                // fused per-row histogram
    }
    __syncthreads();

    int v0 = hist[t], v1 = hist[t + 256];
    lstart[t] = v0; lstart[t + 256] = v1;
    __syncthreads();
    for (int off = 1; off < NBKTP; off <<= 1) {
        int a = (t >= off) ? lstart[t - off] : 0;
        int b = (t + 256 >= off) ? lstart[t + 256 - off] : 0;
        __syncthreads();
        lstart[t] += a; lstart[t + 256] += b;
        __syncthreads();
    }
    int ex0 = lstart[t] - v0, ex1 = lstart[t + 256] - v1;
    __syncthreads();
    lstart[t] = ex0; lstart[t + 256] = ex1;
    if (v0 > 0) baseg[t] = atomicAdd(&bucketCur[t], v0);
    if (v1 > 0) baseg[t + 256] = atomicAdd(&bucketCur[t + 256], v1);
    __syncthreads();

    for (int i = t; i < n; i += 256) {
        int b = bkt[i];
        int l = atomicAdd(&cnt2[b], 1);
        ord[lstart[b] + l] = (unsigned short)i;
    }
    __syncthreads();

    for (int k = t; k < n; k += 256) {
        int i = ord[k];
        int b = bkt[i];
        pairsA[(size_t)baseg[b] + (k - lstart[b])] = staged[i];
    }
}

// ===========================================================================
// scan over rowStart (350K)
// ===========================================================================
__global__ __launch_bounds__(256) void scan_block512(int* __restrict__ data,
                                                     int* __restrict__ blockSums, int n) {
    __shared__ int sm[512];
    int t = threadIdx.x;
    int base = blockIdx.x * 512;
    int i0 = base + t, i1 = base + t + 256;
    int v0 = (i0 < n) ? data[i0] : 0;
    int v1 = (i1 < n) ? data[i1] : 0;
    sm[t] = v0; sm[t + 256] = v1;
    __syncthreads();
    for (int off = 1; off < 512; off <<= 1) {
        int a = (t >= off) ? sm[t - off] : 0;
        int b = (t + 256 >= off) ? sm[t + 256 - off] : 0;
        __syncthreads();
        sm[t] += a; sm[t + 256] += b;
        __syncthreads();
    }
    if (i0 < n) data[i0] = sm[t] - v0;
    if (i1 < n) data[i1] = sm[t + 256] - v1;
    if (t == 255) blockSums[blockIdx.x] = sm[511];
}

__global__ __launch_bounds__(1024) void scan_sums(int* __restrict__ blockSums, int nb) {
    __shared__ int sm[1024];
    int v = (threadIdx.x < nb) ? blockSums[threadIdx.x] : 0;
    sm[threadIdx.x] = v;
    __syncthreads();
    for (int off = 1; off < 1024; off <<= 1) {
        int t = (threadIdx.x >= off) ? sm[threadIdx.x - off] : 0;
        __syncthreads();
        sm[threadIdx.x] += t;
        __syncthreads();
    }
    if (threadIdx.x < nb) blockSums[threadIdx.x] = sm[threadIdx.x] - v;
}

__global__ __launch_bounds__(256) void scan_add512(int* __restrict__ data,
                                                   const int* __restrict__ blockSums,
                                                   int n, int total) {
    int base = blockIdx.x * 512;
    int s = blockSums[blockIdx.x];
#pragma unroll
    for (int k = 0; k < 2; ++k) {
        int i = base + threadIdx.x + k * 256;
        if (i < n) data[i] += s;
    }
    if (blockIdx.x == 0 && threadIdx.x == 0) data[n] = total;
}

// ===========================================================================
// fine scatter: one block per bucket, LDS row cursors; L2-local writes
// ===========================================================================
__global__ __launch_bounds__(512) void fine_pass2(const ull* __restrict__ pairsA,
                                                  const int* __restrict__ rowStart,
                                                  const int* __restrict__ bucketCur,
                                                  ull* __restrict__ pairs) {
    __shared__ int cur[RPB];
    const int b = blockIdx.x, t = threadIdx.x;
    const int r0 = b * RPB;
    const int nr = min(RPB, N_TOT - r0);
    for (int i = t; i < nr; i += 512) cur[i] = rowStart[r0 + i];
    __syncthreads();
    const int base = b * BSTR;
    const int cnt  = bucketCur[b] - base;
    for (int j = t; j < cnt; j += 512) {
        ull e = pairsA[base + j];
        int rLow = (int)((e >> 19) & (RPB - 1));
        int pos = atomicAdd(&cur[rLow], 1);
        pairs[pos] = (e & 0xFFFFFFFF00000000ull) | (e & 0x7FFFFull);
    }
}

// ===========================================================================
// spmm_m: quarter-wave gather (bf16 sources, pair-prefetch) + MFMA W-apply.
//   LAYER 1: gather embBf; tmp12 = bf16(emb+n1); B2 = bf16(lv1)
//   LAYER 2: gather B2;    out = f32(tmp12) + n2
// ===========================================================================
template <int LAYER>
__global__ __launch_bounds__(256) void spmm_m(const ull* __restrict__ pairs,
                                              const int* __restrict__ rowStart,
                                              const unsigned short* __restrict__ embBf,
                                              const unsigned short* __restrict__ B2in,
                                              unsigned short* __restrict__ B2out,
                                              const unsigned short* __restrict__ tmp12in,
                                              unsigned short* __restrict__ tmp12out,
                                              const float* __restrict__ Wui,
                                              const float* __restrict__ Wsoc,
                                              float* __restrict__ out_ui,
                                              float* __restrict__ out_s,
                                              int uiBlocks) {
    __shared__ unsigned short Wb[N_HID][ASTR];        // Wb[c][r] = bf16(W[r][c])
    __shared__ unsigned short agg[4][16][ASTR];
    const int tid = threadIdx.x;
    const bool isUI = (int)blockIdx.x < uiBlocks;
    const int bl    = isUI ? blockIdx.x : blockIdx.x - uiBlocks;
    const int rbeg  = isUI ? bl * BR : N_NODES + bl * BR;
    const int rlim  = isUI ? min(BR, N_NODES - bl * BR) : min(BR, N_USER - bl * BR);

    const float* W = isUI ? Wui : Wsoc;
    for (int idx = tid; idx < N_HID * N_HID; idx += 256) {
        int r = idx >> 6, c = idx & 63;
        Wb[c][r] = f_to_bf(W[idx]);
    }
    __syncthreads();

    const int w = tid >> 6;
    if (w * 16 >= rlim) return;             // rlim is always a multiple of 16
    const int s = tid & 15;
    const int g = (tid >> 4) & 3;

    short8v bfrag[4][2];
#pragma unroll
    for (int nt = 0; nt < 4; ++nt)
#pragma unroll
        for (int kt = 0; kt < 2; ++kt)
            bfrag[nt][kt] = *(const short8v*)&Wb[nt * 16 + s][kt * 32 + g * 8];

    const unsigned short* gsrc = (LAYER == 1) ? embBf : B2in;

    // preload all 4 row extents for this quarter
    int sB[4], eB[4];
#pragma unroll
    for (int i = 0; i < 4; ++i) {
        int r = rbeg + w * 16 + i * 4 + g;
        sB[i] = rowStart[r];
        eB[i] = rowStart[r + 1];
    }

    // prefetch first round of pairs for row 0 (clamped; all reads valid edges)
    ull p[8];
    {
        int lastc = min(max(eB[0] - 1, sB[0]), E_TOT - 1);
#pragma unroll
        for (int k = 0; k < 8; ++k) p[k] = pairs[min(sB[0] + k, lastc)];
    }

    for (int i = 0; i < 4; ++i) {
        float4 acc = make_float4(0.f, 0.f, 0.f, 0.f);
        int j = sB[i], e0 = eB[i];
        bool looped = false;
        while (j < e0) {
            looped = true;
            // issue gathers for current round
            ushort4 raw[8];
#pragma unroll
            for (int k = 0; k < 8; ++k) {
                unsigned c = (unsigned)p[k] & 0x7FFFFu;
                if (LAYER == 1 && c >= N_NODES) c -= N_NODES;
                raw[k] = *(const ushort4*)(gsrc + (size_t)c * N_HID + s * 4);
            }
            float vv[8];
#pragma unroll
            for (int k = 0; k < 8; ++k)
                vv[k] = (j + k < e0) ? __uint_as_float((unsigned)(p[k] >> 32)) : 0.f;

            // prefetch next round (within row, or next row's first round)
            int nj = j + 8;
            bool more = nj < e0;
            int pbase, plast;
            if (more)        { pbase = nj;        plast = e0 - 1; }
            else if (i < 3)  { pbase = sB[i + 1]; plast = max(eB[i + 1] - 1, sB[i + 1]); }
            else             { pbase = 0;         plast = 0; }
            plast = min(plast, E_TOT - 1);
            ull pn[8];
#pragma unroll
            for (int k = 0; k < 8; ++k) pn[k] = pairs[min(pbase + k, plast)];

            // FMA
#pragma unroll
            for (int k = 0; k < 8; ++k) {
                acc.x = fmaf(vv[k], bf_to_f(raw[k].x), acc.x);
                acc.y = fmaf(vv[k], bf_to_f(raw[k].y), acc.y);
                acc.z = fmaf(vv[k], bf_to_f(raw[k].z), acc.z);
                acc.w = fmaf(vv[k], bf_to_f(raw[k].w), acc.w);
            }
#pragma unroll
            for (int k = 0; k < 8; ++k) p[k] = pn[k];
            j = nj;
        }
        if (!looped && i < 3) {              // empty row: prefetch next row now
            int pbase = sB[i + 1];
            int plast = min(max(eB[i + 1] - 1, sB[i + 1]), E_TOT - 1);
#pragma unroll
            for (int k = 0; k < 8; ++k) p[k] = pairs[min(pbase + k, plast)];
        }
        uint2 pk;
        pk.x = pack_bf2(acc.x, acc.y);
        pk.y = pack_bf2(acc.z, acc.w);
        *(uint2*)&agg[w][i * 4 + g][s * 4] = pk;
    }
    asm volatile("s_waitcnt lgkmcnt(0)" ::: "memory");
    __builtin_amdgcn_sched_barrier(0);

    // ---- MFMA: z(16x64) = agg(16x64) @ W(64x64) ----
    short8v a0 = *(const short8v*)&agg[w][s][g * 8];
    short8v a1 = *(const short8v*)&agg[w][s][32 + g * 8];
    f32x4 c[4];
    const f32x4 zero4 = {0.f, 0.f, 0.f, 0.f};
#pragma unroll
    for (int nt = 0; nt < 4; ++nt) {
        c[nt] = __builtin_amdgcn_mfma_f32_16x16x32_bf16(a0, bfrag[nt][0], zero4, 0, 0, 0);
        c[nt] = __builtin_amdgcn_mfma_f32_16x16x32_bf16(a1, bfrag[nt][1], c[nt], 0, 0, 0);
    }

    // ---- leaky + row l2norm (C/D: col = nt*16+s, row = g*4+r) ----
    float lv[4][4];
    float ss[4] = {0.f, 0.f, 0.f, 0.f};
#pragma unroll
    for (int nt = 0; nt < 4; ++nt)
#pragma unroll
        for (int r = 0; r < 4; ++r) {
            float z = c[nt][r];
            float l = (z >= 0.f) ? z : 0.5f * z;
            lv[nt][r] = l;
            ss[r] = fmaf(l, l, ss[r]);
        }
#pragma unroll
    for (int r = 0; r < 4; ++r) {
        float t = ss[r];
        t += __shfl_xor(t, 1, 64);
        t += __shfl_xor(t, 2, 64);
        t += __shfl_xor(t, 4, 64);
        t += __shfl_xor(t, 8, 64);
        ss[r] = 1.f / fmaxf(sqrtf(t), 1e-12f);
    }

    // ---- outputs ----
#pragma unroll
    for (int r = 0; r < 4; ++r) {
        int R = rbeg + w * 16 + g * 4 + r;
        if (LAYER == 1) {
            size_t eRow = isUI ? (size_t)R : (size_t)(R - N_NODES);
#pragma unroll
            for (int nt = 0; nt < 4; ++nt) {
                int col = nt * 16 + s;
                float eb = bf_to_f(embBf[eRow * N_HID + col]);
                tmp12out[(size_t)R * N_HID + col] = f_to_bf(fmaf(lv[nt][r], ss[r], eb));
                B2out[(size_t)R * N_HID + col]    = f_to_bf(lv[nt][r]);
            }
        } else {
            float* op = isUI ? out_ui + (size_t)R * N_HID
                             : out_s  + (size_t)(R - N_NODES) * N_HID;
#pragma unroll
            for (int nt = 0; nt < 4; ++nt) {
                int col = nt * 16 + s;
                float tb = bf_to_f(tmp12in[(size_t)R * N_HID + col]);
                op[col] = fmaf(lv[nt][r], ss[r], tb);
            }
        }
    }
}

// ===========================================================================
// Atomic fallback (only if ws too small for the sorted path)
// ===========================================================================
__global__ __launch_bounds__(256) void init_concat(const float* __restrict__ u,
                                                   const float* __restrict__ it,
                                                   float* __restrict__ A,
                                                   float* __restrict__ out) {
    int i = blockIdx.x * 256 + threadIdx.x;
    const int nu4 = N_USER * N_HID / 4;
    const int nt4 = N_NODES * N_HID / 4;
    if (i >= nt4) return;
    float4 v = (i < nu4) ? ((const float4*)u)[i] : ((const float4*)it)[i - nu4];
    ((float4*)A)[i]   = v;
    ((float4*)out)[i] = v;
}

__global__ __launch_bounds__(256) void copy2(const float* __restrict__ src,
                                             float* __restrict__ d0,
                                             float* __restrict__ d1, int n4) {
    int i = blockIdx.x * 256 + threadIdx.x;
    if (i >= n4) return;
    float4 v = ((const float4*)src)[i];
    ((float4*)d0)[i] = v;
    ((float4*)d1)[i] = v;
}

__global__ __launch_bounds__(256) void gemm64(const float* __restrict__ X,
                                              const float* __restrict__ W,
                                              float* __restrict__ Y, int nrows) {
    __shared__ float Ws[N_HID * N_HID];
    int tid = threadIdx.x;
#pragma unroll
    for (int c = 0; c < 16; ++c) Ws[c * 256 + tid] = W[c * 256 + tid];
    __syncthreads();
    int row = blockIdx.x * 256 + tid;
    if (row >= nrows) return;
    float x[N_HID];
    const float4* xr = (const float4*)(X + (size_t)row * N_HID);
#pragma unroll
    for (int c = 0; c < 16; ++c) {
        float4 v = xr[c];
        x[4*c+0] = v.x; x[4*c+1] = v.y; x[4*c+2] = v.z; x[4*c+3] = v.w;
    }
    float4* y4 = (float4*)(Y + (size_t)row * N_HID);
    for (int jc = 0; jc < 16; ++jc) {
        float4 a = make_float4(0.f,0.f,0.f,0.f);
#pragma unroll
        for (int k = 0; k < N_HID; ++k) {
            float4 wv = *((const float4*)&Ws[k * N_HID + jc * 4]);
            a.x += x[k]*wv.x; a.y += x[k]*wv.y; a.z += x[k]*wv.z; a.w += x[k]*wv.w;
        }
        y4[jc] = a;
    }
}

__global__ __launch_bounds__(256) void spmm_scatter(const int* __restrict__ rows,
                                                    const int* __restrict__ cols,
                                                    const float* __restrict__ vals,
                                                    const float* __restrict__ X,
                                                    float* __restrict__ Y, int nedges) {
    long long t = (long long)blockIdx.x * 256 + threadIdx.x;
    int e = (int)(t >> 6);
    int h = (int)(t & 63);
    if (e >= nedges) return;
    atomicAdd(&Y[rows[e] * N_HID + h], vals[e] * X[cols[e] * N_HID + h]);
}

__global__ __launch_bounds__(256) void leaky_norm_acc(float* __restrict__ Y,
                                                      float* __restrict__ out, int nrows) {
    int row = blockIdx.x * 4 + (threadIdx.x >> 6);
    int h   = threadIdx.x & 63;
    if (row >= nrows) return;
    int idx = row * N_HID + h;
    float v = Y[idx];
    v = (v >= 0.f) ? v : 0.5f * v;
    Y[idx] = v;
    float s = v * v;
#pragma unroll
    for (int off = 32; off > 0; off >>= 1) s += __shfl_xor(s, off, 64);
    out[idx] += v / fmaxf(sqrtf(s), 1e-12f);
}

// ===========================================================================
extern "C" void kernel_launch(void* const* d_in, const int* in_sizes, int n_in,
                              void* d_out, int out_size, void* d_ws, size_t ws_size,
                              hipStream_t stream) {
    const float* user_emb = (const float*)d_in[0];
    const float* item_emb = (const float*)d_in[1];
    const float* ui_w     = (const float*)d_in[2];
    const float* s_w      = (const float*)d_in[3];
    const int*   ui_rows  = (const int*)d_in[4];
    const int*   ui_cols  = (const int*)d_in[5];
    const float* ui_vals  = (const float*)d_in[6];
    const int*   s_rows   = (const int*)d_in[7];
    const int*   s_cols   = (const int*)d_in[8];
    const float* s_vals   = (const float*)d_in[9];

    float* out_ui = (float*)d_out;
    float* out_s  = (float*)d_out + (size_t)N_NODES * N_HID;

    const size_t szUI  = (size_t)N_NODES * N_HID * sizeof(float);     // 64.0 MB
    const size_t szEB  = (size_t)N_NODES * N_HID * sizeof(short);     // 32.0 MB
    const size_t szBF  = (size_t)N_TOT   * N_HID * sizeof(short);     // 44.8 MB
    const size_t rsPad = 1400832;

    const int uiBlocks = (N_NODES + BR - 1) / BR;    // 3907
    const int sBlocks  = (N_USER  + BR - 1) / BR;    // 1563
    const int nbScan   = (N_TOT + 511) / 512;        // 684
    const int nbBin    = (E_TOT + CH - 1) / CH;      // 489
    const int nbEC     = (N_NODES * N_HID / 8 + 255) / 256;  // 7813

    const size_t needBytes = szEB + 2 * szBF + (size_t)E_TOT * 8 + rsPad + 8192 + 8192;

    if (ws_size >= needBytes &&
        (size_t)NBKT * BSTR * 8 <= szBF) {           // pairsA fits in tmp12 alias
        unsigned short* embBf = (unsigned short*)d_ws;
        unsigned short* B2    = (unsigned short*)((char*)d_ws + szEB);
        unsigned short* tmp12 = (unsigned short*)((char*)d_ws + szEB + szBF);
        char* p = (char*)d_ws + szEB + 2 * szBF;
        ull* pairs     = (ull*)p;            p += (size_t)E_TOT * 8;
        int* rowStart  = (int*)p;            p += rsPad;
        int* blockSums = (int*)p;            p += 8192;
        int* bucketCur = (int*)p;
        ull* pairsA    = (ull*)tmp12;        // staging aliases tmp12 (dead until L1 epi)

        // ---- sort + prepass ----
        hipMemsetAsync(rowStart, 0, (size_t)N_TOT * 4, stream);
        seedk<<<1, 512, 0, stream>>>(bucketCur);
        bin_embcast<<<nbBin + nbEC, 256, 0, stream>>>(ui_rows, ui_cols, ui_vals,
                                                      s_rows, s_cols, s_vals,
                                                      bucketCur, rowStart, pairsA,
                                                      user_emb, item_emb, embBf, nbBin);
        scan_block512<<<nbScan, 256, 0, stream>>>(rowStart, blockSums, N_TOT);
        scan_sums<<<1, 1024, 0, stream>>>(blockSums, nbScan);
        scan_add512<<<nbScan, 256, 0, stream>>>(rowStart, blockSums, N_TOT, E_TOT);
        fine_pass2<<<NBKT, 512, 0, stream>>>(pairsA, rowStart, bucketCur, pairs);

        // ---- 2 fused spmm dispatches (MFMA epilogue) ----
        const int grid = uiBlocks + sBlocks;
        spmm_m<1><<<grid, 256, 0, stream>>>(pairs, rowStart, embBf,
                                            nullptr, B2, nullptr, tmp12,
                                            ui_w, s_w, out_ui, out_s, uiBlocks);
        spmm_m<2><<<grid, 256, 0, stream>>>(pairs, rowStart, embBf,
                                            B2, nullptr, tmp12, nullptr,
                                            ui_w + N_HID * N_HID, s_w + N_HID * N_HID,
                                            out_ui, out_s, uiBlocks);
        return;
    }

    // ------------------- fallback: atomic path -------------------
    float* A = (float*)d_ws;
    float* B = (float*)((char*)d_ws + szUI);
    init_concat<<<(N_NODES * N_HID / 4 + 255) / 256, 256, 0, stream>>>(
        user_emb, item_emb, A, out_ui);
    for (int l = 0; l < 2; ++l) {
        gemm64<<<(N_NODES + 255) / 256, 256, 0, stream>>>(
            A, ui_w + l * N_HID * N_HID, B, N_NODES);
        hipMemsetAsync(A, 0, szUI, stream);
        spmm_scatter<<<(int)(((long long)E_UI * 64) / 256), 256, 0, stream>>>(
            ui_rows, ui_cols, ui_vals, B, A, E_UI);
        leaky_norm_acc<<<(N_NODES + 3) / 4, 256, 0, stream>>>(A, out_ui, N_NODES);
    }
    copy2<<<(N_USER * N_HID / 4 + 255) / 256, 256, 0, stream>>>(
        user_emb, A, out_s, N_USER * N_HID / 4);
    const size_t sBytes = (size_t)N_USER * N_HID * sizeof(float);
    for (int l = 0; l < 2; ++l) {
        gemm64<<<(N_USER + 255) / 256, 256, 0, stream>>>(
            A, s_w + l * N_HID * N_HID, B, N_USER);
        hipMemsetAsync(A, 0, sBytes, stream);
        spmm_scatter<<<(int)(((long long)E_S * 64) / 256), 256, 0, stream>>>(
            s_rows, s_cols, s_vals, B, A, E_S);
        leaky_norm_acc<<<(N_USER + 3) / 4, 256, 0, stream>>>(A, out_s, N_USER);
    }
}